// Round 6
// baseline (97.869 us; speedup 1.0000x reference)
//
#include <hip/hip_runtime.h>

#define HH 1024
#define WW 1024
#define NIMG 8
#define TROWS 8   // output rows per block

__device__ __forceinline__ float med3f(float a, float b, float c) {
    return __builtin_amdgcn_fmed3f(a, b, c);
}
__device__ __forceinline__ float min3f(float a, float b, float c) {
    return fminf(fminf(a, b), c);
}
__device__ __forceinline__ float max3f(float a, float b, float c) {
    return fmaxf(fmaxf(a, b), c);
}

// ranks 3,4 of 5
__device__ __forceinline__ void top2(float a, float b, float c, float d, float e,
                                     float& r3, float& r4) {
    float m3 = med3f(a, b, c);
    float h3 = max3f(a, b, c);
    float s2 = med3f(m3, h3, d);
    float s3 = fmaxf(h3, d);
    r3 = med3f(s2, s3, e);
    r4 = fmaxf(s3, e);
}
// ranks 0,1 of 5
__device__ __forceinline__ void bot2(float a, float b, float c, float d, float e,
                                     float& r0, float& r1) {
    float l3 = min3f(a, b, c);
    float m3 = med3f(a, b, c);
    float s0 = fminf(l3, d);
    float s1 = med3f(l3, m3, d);
    r0 = fminf(s0, e);
    r1 = med3f(s0, s1, e);
}
// ranks 2,3,4 of 5
__device__ __forceinline__ void top3(float a, float b, float c, float d, float e,
                                     float& r2, float& r3, float& r4) {
    float l3 = min3f(a, b, c);
    float m3 = med3f(a, b, c);
    float h3 = max3f(a, b, c);
    float s1 = med3f(l3, m3, d);
    float s2 = med3f(m3, h3, d);
    float s3 = fmaxf(h3, d);
    r2 = med3f(s1, s2, e);
    r3 = med3f(s2, s3, e);
    r4 = fmaxf(s3, e);
}
// ranks 0,1,2 of 5
__device__ __forceinline__ void bot3(float a, float b, float c, float d, float e,
                                     float& r0, float& r1, float& r2) {
    float l3 = min3f(a, b, c);
    float m3 = med3f(a, b, c);
    float h3 = max3f(a, b, c);
    float s0 = fminf(l3, d);
    float s1 = med3f(l3, m3, d);
    float s2 = med3f(m3, h3, d);
    r0 = fminf(s0, e);
    r1 = med3f(s0, s1, e);
    r2 = med3f(s1, s2, e);
}
// ranks 1,2,3 of 5
__device__ __forceinline__ void mid3(float a, float b, float c, float d, float e,
                                     float& r1, float& r2, float& r3) {
    float l3 = min3f(a, b, c);
    float m3 = med3f(a, b, c);
    float h3 = max3f(a, b, c);
    float s0 = fminf(l3, d);
    float s1 = med3f(l3, m3, d);
    float s2 = med3f(m3, h3, d);
    float s3 = fmaxf(h3, d);
    r1 = med3f(s0, s1, e);
    r2 = med3f(s1, s2, e);
    r3 = med3f(s2, s3, e);
}

// load one reflect-padded input row (x handled branchlessly per-lane)
__device__ __forceinline__ void loadrow(const float* __restrict__ base, int r,
                                        int tid, int x0, float (&d)[8]) {
    const int rr = (r < 0) ? -r : (r >= HH ? 2 * HH - 2 - r : r);
    const float* rp = base + (size_t)rr * WW;
    const float4 A = *reinterpret_cast<const float4*>(rp + (tid == 0   ? x0 : x0 - 4));
    const float4 B = *reinterpret_cast<const float4*>(rp + x0);
    const float4 C = *reinterpret_cast<const float4*>(rp + (tid == 255 ? x0 : x0 + 4));
    d[0] = (tid == 0)   ? B.z : A.z;   // reflect(-2)=2, reflect(-1)=1
    d[1] = (tid == 0)   ? B.y : A.w;
    d[2] = B.x; d[3] = B.y; d[4] = B.z; d[5] = B.w;
    d[6] = (tid == 255) ? B.z : C.x;   // reflect(1024)=1022, reflect(1025)=1021
    d[7] = (tid == 255) ? B.y : C.y;
}

// 13-candidate exact median-of-25 network over sorted columns (validated R2-R5)
__device__ __forceinline__ void med4net(const float (&S0)[8], const float (&S1)[8],
                                        const float (&S2)[8], const float (&S3)[8],
                                        const float (&S4)[8], float (&med)[4]) {
    #pragma unroll
    for (int j = 0; j < 4; ++j) {
        float r03, r04, r12, r13, r14, r21, r22, r23, r30, r31, r32, r40, r41;
        top2(S0[j], S0[j+1], S0[j+2], S0[j+3], S0[j+4], r03, r04);
        top3(S1[j], S1[j+1], S1[j+2], S1[j+3], S1[j+4], r12, r13, r14);
        mid3(S2[j], S2[j+1], S2[j+2], S2[j+3], S2[j+4], r21, r22, r23);
        bot3(S3[j], S3[j+1], S3[j+2], S3[j+3], S3[j+4], r30, r31, r32);
        bot2(S4[j], S4[j+1], S4[j+2], S4[j+3], S4[j+4], r40, r41);
        float u = fminf(r40, r31), v = fmaxf(r40, r31);
        float w = fminf(v, r32),  x = fmaxf(v, r32);
        float ps0 = r30, ps1 = u, ps2 = w;
        float ps3 = fminf(x, r41), ps4 = fmaxf(x, r41);
        float q0 = fminf(r21, r03);
        float q1 = med3f(r21, r22, r03);
        float q2 = med3f(r22, r23, r03);
        float t1 = fminf(q1, r04);
        float t2 = med3f(q1, q2, r04);
        float t3 = med3f(q2, r23, r04);
        float t4 = fmaxf(r23, r04);
        float Y0 = fmaxf(ps0, q0);
        float Y1 = fmaxf(ps1, t1);
        float X2 = fminf(ps2, t2), Y2 = fmaxf(ps2, t2);
        float X3 = fminf(ps3, t3);
        float X4 = fminf(ps4, t4);
        float L  = max3f(X2, Y0, r12);
        float M  = med3f(X3, Y1, r13);
        float Hc = min3f(X4, Y2, r14);
        med[j] = med3f(L, M, Hc);
    }
}

// One double-step K (K = 0..6): computes median rows m0 = y0-2+2K, m0+1,
// exchanges the previous pair's x-halo (lagged) via LDS, h-gauss on that
// pair, and emits output rows y0-6+2K, +1 for K>=3. All indices static.
template<int K>
__device__ __forceinline__ void dstep(int y0, int tid, int x0,
                                      const float* __restrict__ base,
                                      float* __restrict__ obase,
                                      const float (&wv)[5],
                                      float (&ring)[8][8], float (&hr)[6][4],
                                      float (*lbuf)[1032]) {
    // 1) lagged LDS pair read: med rows y0-4+2K, y0-3+2K (written at K-1)
    float ha[8], hb[8];
    if constexpr (K >= 1) {
        const float* La = lbuf[2 * ((K + 1) & 1)];
        const float* Lb = lbuf[2 * ((K + 1) & 1) + 1];
        const float4 a0 = *reinterpret_cast<const float4*>(&La[x0]);
        const float4 a1 = *reinterpret_cast<const float4*>(&La[x0 + 4]);
        const float4 b0 = *reinterpret_cast<const float4*>(&Lb[x0]);
        const float4 b1 = *reinterpret_cast<const float4*>(&Lb[x0 + 4]);
        ha[0]=a0.x; ha[1]=a0.y; ha[2]=a0.z; ha[3]=a0.w;
        ha[4]=a1.x; ha[5]=a1.y; ha[6]=a1.z; ha[7]=a1.w;
        hb[0]=b0.x; hb[1]=b0.y; hb[2]=b0.z; hb[3]=b0.w;
        hb[4]=b1.x; hb[5]=b1.y; hb[6]=b1.z; hb[7]=b1.w;
    }
    // 2) prefetch next two input rows
    if constexpr (K <= 4) {
        loadrow(base, y0 + 2 + 2 * K, tid, x0, ring[(2 * K + 6) & 7]);
        loadrow(base, y0 + 3 + 2 * K, tid, x0, ring[(2 * K + 7) & 7]);
    }
    // 3) median pair (shared sorted4 of the 4 interior rows)
    if constexpr (K <= 5) {
        constexpr int s0 = (2*K) & 7,     s1 = (2*K + 1) & 7, s2 = (2*K + 2) & 7;
        constexpr int s3 = (2*K + 3) & 7, s4 = (2*K + 4) & 7, s5 = (2*K + 5) & 7;
        float T0[8], T1[8], T2[8], T3[8];  // sorted4 of rows m0-1..m0+2
        #pragma unroll
        for (int c = 0; c < 8; ++c) {
            float b = ring[s1][c], cc = ring[s2][c], d = ring[s3][c], e = ring[s4][c];
            float l3 = min3f(b, cc, d);
            float m3 = med3f(b, cc, d);
            float h3 = max3f(b, cc, d);
            T0[c] = fminf(l3, e);
            T1[c] = med3f(l3, m3, e);
            T2[c] = med3f(m3, h3, e);
            T3[c] = fmaxf(h3, e);
        }
        const int m0 = y0 - 2 + 2 * K;
        float med0[4] = {0.f, 0.f, 0.f, 0.f};
        float med1[4] = {0.f, 0.f, 0.f, 0.f};
        if (m0 >= 0 && m0 < HH) {   // insert row m0-2 -> window m0
            float S0[8], S1[8], S2[8], S3[8], S4[8];
            #pragma unroll
            for (int c = 0; c < 8; ++c) {
                float a = ring[s0][c];
                S0[c] = fminf(T0[c], a);
                S1[c] = med3f(T0[c], T1[c], a);
                S2[c] = med3f(T1[c], T2[c], a);
                S3[c] = med3f(T2[c], T3[c], a);
                S4[c] = fmaxf(T3[c], a);
            }
            med4net(S0, S1, S2, S3, S4, med0);
        }
        const int m1 = m0 + 1;
        if (m1 >= 0 && m1 < HH) {   // insert row m1+2 -> window m1
            float S0[8], S1[8], S2[8], S3[8], S4[8];
            #pragma unroll
            for (int c = 0; c < 8; ++c) {
                float f = ring[s5][c];
                S0[c] = fminf(T0[c], f);
                S1[c] = med3f(T0[c], T1[c], f);
                S2[c] = med3f(T1[c], T2[c], f);
                S3[c] = med3f(T2[c], T3[c], f);
                S4[c] = fmaxf(T3[c], f);
            }
            med4net(S0, S1, S2, S3, S4, med1);
        }
        float* Lw0 = lbuf[2 * (K & 1)];
        float* Lw1 = lbuf[2 * (K & 1) + 1];
        *reinterpret_cast<float2*>(&Lw0[x0 + 2]) = make_float2(med0[0], med0[1]);
        *reinterpret_cast<float2*>(&Lw0[x0 + 4]) = make_float2(med0[2], med0[3]);
        *reinterpret_cast<float2*>(&Lw1[x0 + 2]) = make_float2(med1[0], med1[1]);
        *reinterpret_cast<float2*>(&Lw1[x0 + 4]) = make_float2(med1[2], med1[3]);
    }
    // 4) horizontal gauss on the lagged pair -> hr slots (2K)%6, (2K+1)%6
    if constexpr (K >= 1) {
        #pragma unroll
        for (int j = 0; j < 4; ++j) {
            float h = 0.f;
            #pragma unroll
            for (int c = 0; c < 5; ++c) h = fmaf(wv[c], ha[j + c], h);
            hr[(2 * K) % 6][j] = h;
        }
        #pragma unroll
        for (int j = 0; j < 4; ++j) {
            float h = 0.f;
            #pragma unroll
            for (int c = 0; c < 5; ++c) h = fmaf(wv[c], hb[j + c], h);
            hr[(2 * K + 1) % 6][j] = h;
        }
    }
    // 5) vertical gauss + store output rows o0 = y0-6+2K, o1 = o0+1
    if constexpr (K >= 3) {
        {
            const int o0 = y0 - 6 + 2 * K;
            float a0 = 0.f, a1 = 0.f, a2 = 0.f, a3 = 0.f;
            #pragma unroll
            for (int k = 0; k < 5; ++k) {
                constexpr int base_sl = 2 * K - 4;
                const int   sl = (base_sl + k) % 6;
                const float wy = wv[k];
                a0 = fmaf(wy, hr[sl][0], a0);
                a1 = fmaf(wy, hr[sl][1], a1);
                a2 = fmaf(wy, hr[sl][2], a2);
                a3 = fmaf(wy, hr[sl][3], a3);
            }
            *reinterpret_cast<float4*>(obase + (size_t)o0 * WW + x0) =
                make_float4(a0, a1, a2, a3);
        }
        {
            const int o1 = y0 - 5 + 2 * K;
            float a0 = 0.f, a1 = 0.f, a2 = 0.f, a3 = 0.f;
            #pragma unroll
            for (int k = 0; k < 5; ++k) {
                constexpr int base_sl = 2 * K - 3;
                const int   sl = (base_sl + k) % 6;
                const float wy = wv[k];
                a0 = fmaf(wy, hr[sl][0], a0);
                a1 = fmaf(wy, hr[sl][1], a1);
                a2 = fmaf(wy, hr[sl][2], a2);
                a3 = fmaf(wy, hr[sl][3], a3);
            }
            *reinterpret_cast<float4*>(obase + (size_t)o1 * WW + x0) =
                make_float4(a0, a1, a2, a3);
        }
    }
    if constexpr (K < 6) __syncthreads();
}

// Fused median(reflect) + gaussian(zero-pad). Block = 8 rows x 1024 px.
// img = bid & 7 -> XCD-affine; 1024 blocks -> 4 blocks/CU, 16 waves/CU.
__global__ __launch_bounds__(256, 4) void fused_kernel(const float* __restrict__ in,
                                                       const float* __restrict__ sig,
                                                       float* __restrict__ out) {
    const int bi   = blockIdx.x;
    const int img  = bi & 7;
    const int tile = bi >> 3;
    const int y0   = tile * TROWS;
    const int tid  = threadIdx.x;
    const int x0   = tid * 4;
    const float* base  = in  + (size_t)img * HH * WW;
    float*       obase = out + (size_t)img * HH * WW;

    const float sigma  = sig[0];
    const float inv2s2 = 1.0f / (2.0f * sigma * sigma);
    const float g1 = expf(-1.0f * inv2s2);
    const float g4 = expf(-4.0f * inv2s2);
    const float sn = 1.0f + 2.0f * g1 + 2.0f * g4;
    const float wv[5] = { g4 / sn, g1 / sn, 1.0f / sn, g1 / sn, g4 / sn };

    // 2 double-buffered PAIRS of exchange rows; [0,1] and [1026,1027] are
    // zero borders (x zero-pad); stride 1032 keeps rows 16B-aligned.
    __shared__ float lbuf[4][1032];
    if (tid < 8) {
        const int r = tid >> 1, p = tid & 1;
        lbuf[r][p] = 0.f;
        lbuf[r][1026 + p] = 0.f;
    }

    float ring[8][8];   // raw input rows; row r <-> slot (r - y0 + 4) & 7
    float hr[6][4];     // h-blurred med rows; med row m <-> slot (m - y0 + 4) % 6

    #pragma unroll
    for (int k = 0; k < 6; ++k) loadrow(base, y0 - 4 + k, tid, x0, ring[k]);

    dstep<0>(y0, tid, x0, base, obase, wv, ring, hr, lbuf);
    dstep<1>(y0, tid, x0, base, obase, wv, ring, hr, lbuf);
    dstep<2>(y0, tid, x0, base, obase, wv, ring, hr, lbuf);
    dstep<3>(y0, tid, x0, base, obase, wv, ring, hr, lbuf);
    dstep<4>(y0, tid, x0, base, obase, wv, ring, hr, lbuf);
    dstep<5>(y0, tid, x0, base, obase, wv, ring, hr, lbuf);
    dstep<6>(y0, tid, x0, base, obase, wv, ring, hr, lbuf);
}

extern "C" void kernel_launch(void* const* d_in, const int* in_sizes, int n_in,
                              void* d_out, int out_size, void* d_ws, size_t ws_size,
                              hipStream_t stream) {
    const float* img = (const float*)d_in[0];
    const float* sig = (const float*)d_in[1];
    float* out = (float*)d_out;

    dim3 grid(NIMG * (HH / TROWS));  // 1024 blocks, XCD-affine via bid&7
    dim3 block(256);
    hipLaunchKernelGGL(fused_kernel, grid, block, 0, stream, img, sig, out);
}

// Round 7
// 44.023 us; speedup vs baseline: 2.2232x; 2.2232x over previous
//
#include <hip/hip_runtime.h>

#define HH 1024
#define WW 1024
#define NIMG 8
#define TROWS 8             // output rows per block
#define NSTEP (TROWS + 4)   // 12 median rows per block (incl. +/-2 halo)

__device__ __forceinline__ float med3f(float a, float b, float c) {
    return __builtin_amdgcn_fmed3f(a, b, c);
}
__device__ __forceinline__ float min3f(float a, float b, float c) {
    return fminf(fminf(a, b), c);
}
__device__ __forceinline__ float max3f(float a, float b, float c) {
    return fmaxf(fmaxf(a, b), c);
}

// Full ascending sort5 (12 ops).
__device__ __forceinline__ void sort5(float& a, float& b, float& c, float& d, float& e) {
    float l3 = min3f(a, b, c);
    float m3 = med3f(a, b, c);
    float h3 = max3f(a, b, c);
    float s0 = fminf(l3, d);
    float s1 = med3f(l3, m3, d);
    float s2 = med3f(m3, h3, d);
    float s3 = fmaxf(h3, d);
    float r0 = fminf(s0, e);
    float r1 = med3f(s0, s1, e);
    float r2 = med3f(s1, s2, e);
    float r3 = med3f(s2, s3, e);
    float r4 = fmaxf(s3, e);
    a = r0; b = r1; c = r2; d = r3; e = r4;
}
// ranks 3,4 of 5
__device__ __forceinline__ void top2(float a, float b, float c, float d, float e,
                                     float& r3, float& r4) {
    float m3 = med3f(a, b, c);
    float h3 = max3f(a, b, c);
    float s2 = med3f(m3, h3, d);
    float s3 = fmaxf(h3, d);
    r3 = med3f(s2, s3, e);
    r4 = fmaxf(s3, e);
}
// ranks 0,1 of 5
__device__ __forceinline__ void bot2(float a, float b, float c, float d, float e,
                                     float& r0, float& r1) {
    float l3 = min3f(a, b, c);
    float m3 = med3f(a, b, c);
    float s0 = fminf(l3, d);
    float s1 = med3f(l3, m3, d);
    r0 = fminf(s0, e);
    r1 = med3f(s0, s1, e);
}
// ranks 2,3,4 of 5
__device__ __forceinline__ void top3(float a, float b, float c, float d, float e,
                                     float& r2, float& r3, float& r4) {
    float l3 = min3f(a, b, c);
    float m3 = med3f(a, b, c);
    float h3 = max3f(a, b, c);
    float s1 = med3f(l3, m3, d);
    float s2 = med3f(m3, h3, d);
    float s3 = fmaxf(h3, d);
    r2 = med3f(s1, s2, e);
    r3 = med3f(s2, s3, e);
    r4 = fmaxf(s3, e);
}
// ranks 0,1,2 of 5
__device__ __forceinline__ void bot3(float a, float b, float c, float d, float e,
                                     float& r0, float& r1, float& r2) {
    float l3 = min3f(a, b, c);
    float m3 = med3f(a, b, c);
    float h3 = max3f(a, b, c);
    float s0 = fminf(l3, d);
    float s1 = med3f(l3, m3, d);
    float s2 = med3f(m3, h3, d);
    r0 = fminf(s0, e);
    r1 = med3f(s0, s1, e);
    r2 = med3f(s1, s2, e);
}
// ranks 1,2,3 of 5
__device__ __forceinline__ void mid3(float a, float b, float c, float d, float e,
                                     float& r1, float& r2, float& r3) {
    float l3 = min3f(a, b, c);
    float m3 = med3f(a, b, c);
    float h3 = max3f(a, b, c);
    float s0 = fminf(l3, d);
    float s1 = med3f(l3, m3, d);
    float s2 = med3f(m3, h3, d);
    float s3 = fmaxf(h3, d);
    r1 = med3f(s0, s1, e);
    r2 = med3f(s1, s2, e);
    r3 = med3f(s2, s3, e);
}

// load one reflect-padded input row (x handled branchlessly per-lane)
__device__ __forceinline__ void loadrow(const float* __restrict__ base, int r,
                                        int tid, int x0, float (&d)[8]) {
    const int rr = (r < 0) ? -r : (r >= HH ? 2 * HH - 2 - r : r);
    const float* rp = base + (size_t)rr * WW;
    const float4 A = *reinterpret_cast<const float4*>(rp + (tid == 0   ? x0 : x0 - 4));
    const float4 B = *reinterpret_cast<const float4*>(rp + x0);
    const float4 C = *reinterpret_cast<const float4*>(rp + (tid == 255 ? x0 : x0 + 4));
    d[0] = (tid == 0)   ? B.z : A.z;   // reflect(-2)=2, reflect(-1)=1
    d[1] = (tid == 0)   ? B.y : A.w;
    d[2] = B.x; d[3] = B.y; d[4] = B.z; d[5] = B.w;
    d[6] = (tid == 255) ? B.z : C.x;   // reflect(1024)=1022, reflect(1025)=1021
    d[7] = (tid == 255) ? B.y : C.y;
}

// 13-candidate exact median network over ring slots (P..P+4)%6 (verified R2-R5)
template<int P>
__device__ __forceinline__ void median4(const float (&ring)[6][8], float (&med)[4]) {
    float S0[8], S1[8], S2[8], S3[8], S4[8];
    #pragma unroll
    for (int c = 0; c < 8; ++c) {
        float a = ring[P % 6][c];
        float b = ring[(P + 1) % 6][c];
        float g = ring[(P + 2) % 6][c];
        float d = ring[(P + 3) % 6][c];
        float e = ring[(P + 4) % 6][c];
        sort5(a, b, g, d, e);
        S0[c] = a; S1[c] = b; S2[c] = g; S3[c] = d; S4[c] = e;
    }
    #pragma unroll
    for (int j = 0; j < 4; ++j) {
        float r03, r04, r12, r13, r14, r21, r22, r23, r30, r31, r32, r40, r41;
        top2(S0[j], S0[j+1], S0[j+2], S0[j+3], S0[j+4], r03, r04);
        top3(S1[j], S1[j+1], S1[j+2], S1[j+3], S1[j+4], r12, r13, r14);
        mid3(S2[j], S2[j+1], S2[j+2], S2[j+3], S2[j+4], r21, r22, r23);
        bot3(S3[j], S3[j+1], S3[j+2], S3[j+3], S3[j+4], r30, r31, r32);
        bot2(S4[j], S4[j+1], S4[j+2], S4[j+3], S4[j+4], r40, r41);
        float u = fminf(r40, r31), v = fmaxf(r40, r31);
        float w = fminf(v, r32),  x = fmaxf(v, r32);
        float ps0 = r30, ps1 = u, ps2 = w;
        float ps3 = fminf(x, r41), ps4 = fmaxf(x, r41);
        float q0 = fminf(r21, r03);
        float q1 = med3f(r21, r22, r03);
        float q2 = med3f(r22, r23, r03);
        float t1 = fminf(q1, r04);
        float t2 = med3f(q1, q2, r04);
        float t3 = med3f(q2, r23, r04);
        float t4 = fmaxf(r23, r04);
        float Y0 = fmaxf(ps0, q0);
        float Y1 = fmaxf(ps1, t1);
        float X2 = fminf(ps2, t2), Y2 = fmaxf(ps2, t2);
        float X3 = fminf(ps3, t3);
        float X4 = fminf(ps4, t4);
        float L  = max3f(X2, Y0, r12);
        float M  = med3f(X3, Y1, r13);
        float Hc = min3f(X4, Y2, r14);
        med[j] = med3f(L, M, Hc);
    }
}

// One pipeline step, P = s % 6 (template -> all ring/hr indices static).
// Lagged LDS exchange: read med row s-1 at top (latency hidden by the median
// network), write med row s, barrier at END of step. 2 buffers are race-free:
// reader of slot s%2 (step s+1) drains before writer (step s+2) crosses
// barrier_{s+1}.
template<int P>
__device__ __forceinline__ void step(int s, int y0, int tid, int x0,
                                     const float* __restrict__ base,
                                     float* __restrict__ obase,
                                     const float (&wv)[5],
                                     float (&ring)[6][8], float (&hr)[6][4],
                                     float (*lbuf)[1040]) {
    // lagged halo read for med row s-1 (written last step, synced by barrier)
    float hh[8];
    if (s >= 1) {
        const float* Lb = lbuf[(s + 1) & 1];
        const float4 Ha = *reinterpret_cast<const float4*>(&Lb[x0]);
        const float4 Hb = *reinterpret_cast<const float4*>(&Lb[x0 + 4]);
        hh[0] = Ha.x; hh[1] = Ha.y; hh[2] = Ha.z; hh[3] = Ha.w;
        hh[4] = Hb.x; hh[5] = Hb.y; hh[6] = Hb.z; hh[7] = Hb.w;
    }
    // prefetch next input row (consumed next step)
    if (s < NSTEP - 1) loadrow(base, y0 + s + 1, tid, x0, ring[(P + 5) % 6]);

    // median row index m = y0 - 2 + s; zero outside [0,HH) (gauss zero-pad)
    float med[4] = {0.f, 0.f, 0.f, 0.f};
    const int m = y0 - 2 + s;
    if (s < NSTEP && m >= 0 && m < HH) median4<P>(ring, med);

    if (s < NSTEP) {
        float* Lw = lbuf[s & 1];
        *reinterpret_cast<float2*>(&Lw[x0 + 2]) = make_float2(med[0], med[1]);
        *reinterpret_cast<float2*>(&Lw[x0 + 4]) = make_float2(med[2], med[3]);
    }

    // horizontal gauss for med row s-1 -> hr slot (s-1)%6 = (P+5)%6
    if (s >= 1) {
        #pragma unroll
        for (int j = 0; j < 4; ++j) {
            float h = 0.f;
            #pragma unroll
            for (int c = 0; c < 5; ++c) h = fmaf(wv[c], hh[j + c], h);
            hr[(P + 5) % 6][j] = h;
        }
    }

    // vertical gauss + store output row o = y0 + s - 5
    if (s >= 5) {
        const int o = y0 + s - 5;
        float a0 = 0.f, a1 = 0.f, a2 = 0.f, a3 = 0.f;
        #pragma unroll
        for (int k = 0; k < 5; ++k) {
            const int   sl = (P + 1 + k) % 6;  // h of med row (s-5+k)
            const float wy = wv[k];
            a0 = fmaf(wy, hr[sl][0], a0);
            a1 = fmaf(wy, hr[sl][1], a1);
            a2 = fmaf(wy, hr[sl][2], a2);
            a3 = fmaf(wy, hr[sl][3], a3);
        }
        *reinterpret_cast<float4*>(obase + (size_t)o * WW + x0) =
            make_float4(a0, a1, a2, a3);
    }
    __syncthreads();
}

// Fused median(reflect) + gaussian(zero-pad). Block = 8 rows x 1024 px.
// img = bid & 7 -> XCD-affine; 1024 blocks -> 4 blocks/CU, 16 waves/CU.
__global__ __launch_bounds__(256, 2) void fused_kernel(const float* __restrict__ in,
                                                       const float* __restrict__ sig,
                                                       float* __restrict__ out) {
    const int bi   = blockIdx.x;
    const int img  = bi & 7;
    const int tile = bi >> 3;
    const int y0   = tile * TROWS;
    const int tid  = threadIdx.x;
    const int x0   = tid * 4;
    const float* base  = in  + (size_t)img * HH * WW;
    float*       obase = out + (size_t)img * HH * WW;

    const float sigma  = sig[0];
    const float inv2s2 = 1.0f / (2.0f * sigma * sigma);
    const float g1 = expf(-1.0f * inv2s2);
    const float g4 = expf(-4.0f * inv2s2);
    const float sn = 1.0f + 2.0f * g1 + 2.0f * g4;
    const float wv[5] = { g4 / sn, g1 / sn, 1.0f / sn, g1 / sn, g4 / sn };

    // double-buffered exchange rows; [0,1] and [1026,1027] are zero borders;
    // row stride 1040 keeps both buffers 16B-aligned.
    __shared__ float lbuf[2][1040];
    if (tid < 2) {
        lbuf[tid][0] = 0.f; lbuf[tid][1] = 0.f;
        lbuf[tid][1026] = 0.f; lbuf[tid][1027] = 0.f;
    }

    float ring[6][8];   // input rows; row y0+t <-> slot (t+4)%6
    float hr[6][4];     // h-blurred med rows; med row j <-> slot j%6

    #pragma unroll
    for (int k = 0; k < 5; ++k) loadrow(base, y0 - 4 + k, tid, x0, ring[k]);

    // s = 0..11 : 2 x 6 statically-instantiated phases
    for (int outer = 0; outer < 2; ++outer) {
        const int sb = outer * 6;
        step<0>(sb + 0, y0, tid, x0, base, obase, wv, ring, hr, lbuf);
        step<1>(sb + 1, y0, tid, x0, base, obase, wv, ring, hr, lbuf);
        step<2>(sb + 2, y0, tid, x0, base, obase, wv, ring, hr, lbuf);
        step<3>(sb + 3, y0, tid, x0, base, obase, wv, ring, hr, lbuf);
        step<4>(sb + 4, y0, tid, x0, base, obase, wv, ring, hr, lbuf);
        step<5>(sb + 5, y0, tid, x0, base, obase, wv, ring, hr, lbuf);
    }
    // tail: s = 12 (last h-gauss + last output row)
    step<0>(12, y0, tid, x0, base, obase, wv, ring, hr, lbuf);
}

extern "C" void kernel_launch(void* const* d_in, const int* in_sizes, int n_in,
                              void* d_out, int out_size, void* d_ws, size_t ws_size,
                              hipStream_t stream) {
    const float* img = (const float*)d_in[0];
    const float* sig = (const float*)d_in[1];
    float* out = (float*)d_out;

    dim3 grid(NIMG * (HH / TROWS));  // 1024 blocks, XCD-affine via bid&7
    dim3 block(256);
    hipLaunchKernelGGL(fused_kernel, grid, block, 0, stream, img, sig, out);
}

// Round 8
// 37.202 us; speedup vs baseline: 2.6308x; 1.1834x over previous
//
#include <hip/hip_runtime.h>

#define HH 1024
#define WW 1024
#define NIMG 8
#define TROWS 16            // output rows per block
#define NSTEP (TROWS + 4)   // 20 median rows per block (incl. +/-2 halo)

__device__ __forceinline__ float med3f(float a, float b, float c) {
    return __builtin_amdgcn_fmed3f(a, b, c);
}
__device__ __forceinline__ float min3f(float a, float b, float c) {
    return fminf(fminf(a, b), c);
}
__device__ __forceinline__ float max3f(float a, float b, float c) {
    return fmaxf(fmaxf(a, b), c);
}

// ranks 3,4 of 5
__device__ __forceinline__ void top2(float a, float b, float c, float d, float e,
                                     float& r3, float& r4) {
    float m3 = med3f(a, b, c);
    float h3 = max3f(a, b, c);
    float s2 = med3f(m3, h3, d);
    float s3 = fmaxf(h3, d);
    r3 = med3f(s2, s3, e);
    r4 = fmaxf(s3, e);
}
// ranks 0,1 of 5
__device__ __forceinline__ void bot2(float a, float b, float c, float d, float e,
                                     float& r0, float& r1) {
    float l3 = min3f(a, b, c);
    float m3 = med3f(a, b, c);
    float s0 = fminf(l3, d);
    float s1 = med3f(l3, m3, d);
    r0 = fminf(s0, e);
    r1 = med3f(s0, s1, e);
}
// ranks 2,3,4 of 5
__device__ __forceinline__ void top3(float a, float b, float c, float d, float e,
                                     float& r2, float& r3, float& r4) {
    float l3 = min3f(a, b, c);
    float m3 = med3f(a, b, c);
    float h3 = max3f(a, b, c);
    float s1 = med3f(l3, m3, d);
    float s2 = med3f(m3, h3, d);
    float s3 = fmaxf(h3, d);
    r2 = med3f(s1, s2, e);
    r3 = med3f(s2, s3, e);
    r4 = fmaxf(s3, e);
}
// ranks 0,1,2 of 5
__device__ __forceinline__ void bot3(float a, float b, float c, float d, float e,
                                     float& r0, float& r1, float& r2) {
    float l3 = min3f(a, b, c);
    float m3 = med3f(a, b, c);
    float h3 = max3f(a, b, c);
    float s0 = fminf(l3, d);
    float s1 = med3f(l3, m3, d);
    float s2 = med3f(m3, h3, d);
    r0 = fminf(s0, e);
    r1 = med3f(s0, s1, e);
    r2 = med3f(s1, s2, e);
}
// ranks 1,2,3 of 5
__device__ __forceinline__ void mid3(float a, float b, float c, float d, float e,
                                     float& r1, float& r2, float& r3) {
    float l3 = min3f(a, b, c);
    float m3 = med3f(a, b, c);
    float h3 = max3f(a, b, c);
    float s0 = fminf(l3, d);
    float s1 = med3f(l3, m3, d);
    float s2 = med3f(m3, h3, d);
    float s3 = fmaxf(h3, d);
    r1 = med3f(s0, s1, e);
    r2 = med3f(s1, s2, e);
    r3 = med3f(s2, s3, e);
}

// load one reflect-padded input row (x handled branchlessly per-lane)
__device__ __forceinline__ void loadrow(const float* __restrict__ base, int r,
                                        int tid, int x0, float (&d)[8]) {
    const int rr = (r < 0) ? -r : (r >= HH ? 2 * HH - 2 - r : r);
    const float* rp = base + (size_t)rr * WW;
    const float4 A = *reinterpret_cast<const float4*>(rp + (tid == 0   ? x0 : x0 - 4));
    const float4 B = *reinterpret_cast<const float4*>(rp + x0);
    const float4 C = *reinterpret_cast<const float4*>(rp + (tid == 255 ? x0 : x0 + 4));
    d[0] = (tid == 0)   ? B.z : A.z;   // reflect(-2)=2, reflect(-1)=1
    d[1] = (tid == 0)   ? B.y : A.w;
    d[2] = B.x; d[3] = B.y; d[4] = B.z; d[5] = B.w;
    d[6] = (tid == 255) ? B.z : C.x;   // reflect(1024)=1022, reflect(1025)=1021
    d[7] = (tid == 255) ? B.y : C.y;
}

// 13-candidate exact median-of-25 network over sorted columns (validated R2-R6)
__device__ __forceinline__ void med4net(const float (&S0)[8], const float (&S1)[8],
                                        const float (&S2)[8], const float (&S3)[8],
                                        const float (&S4)[8], float (&med)[4]) {
    #pragma unroll
    for (int j = 0; j < 4; ++j) {
        float r03, r04, r12, r13, r14, r21, r22, r23, r30, r31, r32, r40, r41;
        top2(S0[j], S0[j+1], S0[j+2], S0[j+3], S0[j+4], r03, r04);
        top3(S1[j], S1[j+1], S1[j+2], S1[j+3], S1[j+4], r12, r13, r14);
        mid3(S2[j], S2[j+1], S2[j+2], S2[j+3], S2[j+4], r21, r22, r23);
        bot3(S3[j], S3[j+1], S3[j+2], S3[j+3], S3[j+4], r30, r31, r32);
        bot2(S4[j], S4[j+1], S4[j+2], S4[j+3], S4[j+4], r40, r41);
        float u = fminf(r40, r31), v = fmaxf(r40, r31);
        float w = fminf(v, r32),  x = fmaxf(v, r32);
        float ps0 = r30, ps1 = u, ps2 = w;
        float ps3 = fminf(x, r41), ps4 = fmaxf(x, r41);
        float q0 = fminf(r21, r03);
        float q1 = med3f(r21, r22, r03);
        float q2 = med3f(r22, r23, r03);
        float t1 = fminf(q1, r04);
        float t2 = med3f(q1, q2, r04);
        float t3 = med3f(q2, r23, r04);
        float t4 = fmaxf(r23, r04);
        float Y0 = fmaxf(ps0, q0);
        float Y1 = fmaxf(ps1, t1);
        float X2 = fminf(ps2, t2), Y2 = fmaxf(ps2, t2);
        float X3 = fminf(ps3, t3);
        float X4 = fminf(ps4, t4);
        float L  = max3f(X2, Y0, r12);
        float M  = med3f(X3, Y1, r13);
        float Hc = min3f(X4, Y2, r14);
        med[j] = med3f(L, M, Hc);
    }
}

// Double-step K (K = 0..10): computes median rows m0 = y0-2+2K and m0+1
// (shared sorted4 of their 4 common rows), lagged LDS x-halo exchange of the
// previous pair, h-gauss on that pair, outputs rows y0-6+2K, +1 for K>=3.
// All ring/hr/LDS indices compile-time. Barrier at end (except last step).
template<int K>
__device__ __forceinline__ void dstep(int y0, int tid, int x0,
                                      const float* __restrict__ base,
                                      float* __restrict__ obase,
                                      const float (&wv)[5],
                                      float (&ring)[8][8], float (&hr)[6][4],
                                      float (*lbuf)[1032]) {
    // 1) lagged LDS pair read: med rows y0-4+2K, y0-3+2K (written at K-1)
    float ha[8], hb[8];
    if constexpr (K >= 1) {
        const float* La = lbuf[2 * ((K + 1) & 1)];
        const float* Lb = lbuf[2 * ((K + 1) & 1) + 1];
        const float4 a0 = *reinterpret_cast<const float4*>(&La[x0]);
        const float4 a1 = *reinterpret_cast<const float4*>(&La[x0 + 4]);
        const float4 b0 = *reinterpret_cast<const float4*>(&Lb[x0]);
        const float4 b1 = *reinterpret_cast<const float4*>(&Lb[x0 + 4]);
        ha[0]=a0.x; ha[1]=a0.y; ha[2]=a0.z; ha[3]=a0.w;
        ha[4]=a1.x; ha[5]=a1.y; ha[6]=a1.z; ha[7]=a1.w;
        hb[0]=b0.x; hb[1]=b0.y; hb[2]=b0.z; hb[3]=b0.w;
        hb[4]=b1.x; hb[5]=b1.y; hb[6]=b1.z; hb[7]=b1.w;
    }
    // 2) prefetch next two input rows
    if constexpr (K <= 8) {
        loadrow(base, y0 + 2 + 2 * K, tid, x0, ring[(2 * K + 6) & 7]);
        loadrow(base, y0 + 3 + 2 * K, tid, x0, ring[(2 * K + 7) & 7]);
    }
    // 3) median pair (shared sorted4 of rows m0-1..m0+2 = slots s1..s4)
    if constexpr (K <= 9) {
        constexpr int s0 = (2*K) & 7,     s1 = (2*K + 1) & 7, s2 = (2*K + 2) & 7;
        constexpr int s3 = (2*K + 3) & 7, s4 = (2*K + 4) & 7, s5 = (2*K + 5) & 7;
        float T0[8], T1[8], T2[8], T3[8];
        #pragma unroll
        for (int c = 0; c < 8; ++c) {
            float b = ring[s1][c], cc = ring[s2][c], d = ring[s3][c], e = ring[s4][c];
            float l3 = min3f(b, cc, d);
            float m3 = med3f(b, cc, d);
            float h3 = max3f(b, cc, d);
            T0[c] = fminf(l3, e);
            T1[c] = med3f(l3, m3, e);
            T2[c] = med3f(m3, h3, e);
            T3[c] = fmaxf(h3, e);
        }
        const int m0 = y0 - 2 + 2 * K;
        float med0[4] = {0.f, 0.f, 0.f, 0.f};
        float med1[4] = {0.f, 0.f, 0.f, 0.f};
        if (m0 >= 0 && m0 < HH) {   // insert row m0-2 (slot s0) -> window m0
            float S0[8], S1[8], S2[8], S3[8], S4[8];
            #pragma unroll
            for (int c = 0; c < 8; ++c) {
                float a = ring[s0][c];
                S0[c] = fminf(T0[c], a);
                S1[c] = med3f(T0[c], T1[c], a);
                S2[c] = med3f(T1[c], T2[c], a);
                S3[c] = med3f(T2[c], T3[c], a);
                S4[c] = fmaxf(T3[c], a);
            }
            med4net(S0, S1, S2, S3, S4, med0);
        }
        const int m1 = m0 + 1;
        if (m1 >= 0 && m1 < HH) {   // insert row m1+2 (slot s5) -> window m1
            float S0[8], S1[8], S2[8], S3[8], S4[8];
            #pragma unroll
            for (int c = 0; c < 8; ++c) {
                float f = ring[s5][c];
                S0[c] = fminf(T0[c], f);
                S1[c] = med3f(T0[c], T1[c], f);
                S2[c] = med3f(T1[c], T2[c], f);
                S3[c] = med3f(T2[c], T3[c], f);
                S4[c] = fmaxf(T3[c], f);
            }
            med4net(S0, S1, S2, S3, S4, med1);
        }
        float* Lw0 = lbuf[2 * (K & 1)];
        float* Lw1 = lbuf[2 * (K & 1) + 1];
        *reinterpret_cast<float2*>(&Lw0[x0 + 2]) = make_float2(med0[0], med0[1]);
        *reinterpret_cast<float2*>(&Lw0[x0 + 4]) = make_float2(med0[2], med0[3]);
        *reinterpret_cast<float2*>(&Lw1[x0 + 2]) = make_float2(med1[0], med1[1]);
        *reinterpret_cast<float2*>(&Lw1[x0 + 4]) = make_float2(med1[2], med1[3]);
    }
    // 4) horizontal gauss on the lagged pair -> hr slots (2K)%6, (2K+1)%6
    if constexpr (K >= 1) {
        #pragma unroll
        for (int j = 0; j < 4; ++j) {
            float h = 0.f;
            #pragma unroll
            for (int c = 0; c < 5; ++c) h = fmaf(wv[c], ha[j + c], h);
            hr[(2 * K) % 6][j] = h;
        }
        #pragma unroll
        for (int j = 0; j < 4; ++j) {
            float h = 0.f;
            #pragma unroll
            for (int c = 0; c < 5; ++c) h = fmaf(wv[c], hb[j + c], h);
            hr[(2 * K + 1) % 6][j] = h;
        }
    }
    // 5) vertical gauss + store output rows o0 = y0-6+2K, o1 = o0+1
    if constexpr (K >= 3) {
        {
            float a0 = 0.f, a1 = 0.f, a2 = 0.f, a3 = 0.f;
            #pragma unroll
            for (int k = 0; k < 5; ++k) {
                const int   sl = (2 * K - 4 + k) % 6;
                const float wy = wv[k];
                a0 = fmaf(wy, hr[sl][0], a0);
                a1 = fmaf(wy, hr[sl][1], a1);
                a2 = fmaf(wy, hr[sl][2], a2);
                a3 = fmaf(wy, hr[sl][3], a3);
            }
            const int o0 = y0 - 6 + 2 * K;
            *reinterpret_cast<float4*>(obase + (size_t)o0 * WW + x0) =
                make_float4(a0, a1, a2, a3);
        }
        {
            float a0 = 0.f, a1 = 0.f, a2 = 0.f, a3 = 0.f;
            #pragma unroll
            for (int k = 0; k < 5; ++k) {
                const int   sl = (2 * K - 3 + k) % 6;
                const float wy = wv[k];
                a0 = fmaf(wy, hr[sl][0], a0);
                a1 = fmaf(wy, hr[sl][1], a1);
                a2 = fmaf(wy, hr[sl][2], a2);
                a3 = fmaf(wy, hr[sl][3], a3);
            }
            const int o1 = y0 - 5 + 2 * K;
            *reinterpret_cast<float4*>(obase + (size_t)o1 * WW + x0) =
                make_float4(a0, a1, a2, a3);
        }
    }
    if constexpr (K < 10) __syncthreads();
}

// Fused median(reflect) + gaussian(zero-pad). Block = 16 rows x 1024 px.
// img = bid & 7 -> XCD-affine. 512 blocks; 10 barriers/block (vs 21 in R5).
__global__ __launch_bounds__(256, 2) void fused_kernel(const float* __restrict__ in,
                                                       const float* __restrict__ sig,
                                                       float* __restrict__ out) {
    const int bi   = blockIdx.x;
    const int img  = bi & 7;
    const int tile = bi >> 3;
    const int y0   = tile * TROWS;
    const int tid  = threadIdx.x;
    const int x0   = tid * 4;
    const float* base  = in  + (size_t)img * HH * WW;
    float*       obase = out + (size_t)img * HH * WW;

    const float sigma  = sig[0];
    const float inv2s2 = 1.0f / (2.0f * sigma * sigma);
    const float g1 = expf(-1.0f * inv2s2);
    const float g4 = expf(-4.0f * inv2s2);
    const float sn = 1.0f + 2.0f * g1 + 2.0f * g4;
    const float wv[5] = { g4 / sn, g1 / sn, 1.0f / sn, g1 / sn, g4 / sn };

    // 2 double-buffered PAIRS of exchange rows; [0,1] and [1026,1027] are
    // zero borders (x zero-pad); stride 1032 keeps rows 16B-aligned.
    __shared__ float lbuf[4][1032];
    if (tid < 8) {
        const int r = tid >> 1, p = tid & 1;
        lbuf[r][p] = 0.f;
        lbuf[r][1026 + p] = 0.f;
    }

    float ring[8][8];   // raw input rows; row r <-> slot (r - y0 + 4) & 7
    float hr[6][4];     // h-blurred med rows; med row m <-> slot (m - y0 + 4) % 6

    #pragma unroll
    for (int k = 0; k < 6; ++k) loadrow(base, y0 - 4 + k, tid, x0, ring[k]);

    dstep<0>(y0, tid, x0, base, obase, wv, ring, hr, lbuf);
    dstep<1>(y0, tid, x0, base, obase, wv, ring, hr, lbuf);
    dstep<2>(y0, tid, x0, base, obase, wv, ring, hr, lbuf);
    dstep<3>(y0, tid, x0, base, obase, wv, ring, hr, lbuf);
    dstep<4>(y0, tid, x0, base, obase, wv, ring, hr, lbuf);
    dstep<5>(y0, tid, x0, base, obase, wv, ring, hr, lbuf);
    dstep<6>(y0, tid, x0, base, obase, wv, ring, hr, lbuf);
    dstep<7>(y0, tid, x0, base, obase, wv, ring, hr, lbuf);
    dstep<8>(y0, tid, x0, base, obase, wv, ring, hr, lbuf);
    dstep<9>(y0, tid, x0, base, obase, wv, ring, hr, lbuf);
    dstep<10>(y0, tid, x0, base, obase, wv, ring, hr, lbuf);
}

extern "C" void kernel_launch(void* const* d_in, const int* in_sizes, int n_in,
                              void* d_out, int out_size, void* d_ws, size_t ws_size,
                              hipStream_t stream) {
    const float* img = (const float*)d_in[0];
    const float* sig = (const float*)d_in[1];
    float* out = (float*)d_out;

    dim3 grid(NIMG * (HH / TROWS));  // 512 blocks, XCD-affine via bid&7
    dim3 block(256);
    hipLaunchKernelGGL(fused_kernel, grid, block, 0, stream, img, sig, out);
}